// Round 1
// baseline (56.147 us; speedup 1.0000x reference)
//
#include <hip/hip_runtime.h>

// Problem: out[0] = beta_0 + (8 * 0.2^3) * sum_{k<7, i>j} x[k,i,j]
// x: (7,64,64) fp32 = 28672 floats = 7168 float4. Tiny, launch-latency bound.
// Single block, 1024 threads (16 waves), 7 float4 loads/thread, shuffle+LDS
// reduce, no atomics (deterministic), no workspace.

__global__ __launch_bounds__(1024) void candemann_parafac_reduce(
    const float* __restrict__ x,
    const float* __restrict__ beta0,
    float* __restrict__ out) {

    const float4* __restrict__ x4 = reinterpret_cast<const float4*>(x);
    const int tid = threadIdx.x;

    float s = 0.0f;
    #pragma unroll
    for (int it = 0; it < 7; ++it) {
        const int f = it * 1024 + tid;     // float4 index, 0..7167
        const float4 v = x4[f];
        const int base = f << 2;           // flat float index (multiple of 4)
        const int i = (base >> 6) & 63;    // row, shared by all 4 elems
        const int j = base & 63;           // col of .x; cols are j..j+3
        // strictly lower triangular: keep element iff i > col
        s += (i > j    ) ? v.x : 0.0f;
        s += (i > j + 1) ? v.y : 0.0f;
        s += (i > j + 2) ? v.z : 0.0f;
        s += (i > j + 3) ? v.w : 0.0f;
    }

    // 64-lane wave reduction (wave = 64 on CDNA)
    #pragma unroll
    for (int off = 32; off > 0; off >>= 1)
        s += __shfl_down(s, off, 64);

    __shared__ float wave_sums[16];
    const int wave = tid >> 6;
    const int lane = tid & 63;
    if (lane == 0) wave_sums[wave] = s;
    __syncthreads();

    if (tid == 0) {
        float tot = 0.0f;
        #pragma unroll
        for (int w = 0; w < 16; ++w) tot += wave_sums[w];
        // cp_sum = RANK * 0.2^3 = 0.064 (exact to fp32 resolution)
        out[0] = beta0[0] + 0.064f * tot;
    }
}

extern "C" void kernel_launch(void* const* d_in, const int* in_sizes, int n_in,
                              void* d_out, int out_size, void* d_ws, size_t ws_size,
                              hipStream_t stream) {
    const float* x     = (const float*)d_in[0];  // (7,64,64) fp32
    const float* beta0 = (const float*)d_in[1];  // scalar fp32
    float* out = (float*)d_out;

    candemann_parafac_reduce<<<1, 1024, 0, stream>>>(x, beta0, out);
}